// Round 5
// baseline (993.009 us; speedup 1.0000x reference)
//
#include <hip/hip_runtime.h>
#include <cstddef>

#define B_SZ 2
#define S_LEN 1024
#define NH 16
#define HD 64
#define DIM 1024
#define HID 2816
#define NVOCAB 32000

typedef __attribute__((ext_vector_type(8))) short short8;
typedef __attribute__((ext_vector_type(4))) float f32x4;
typedef unsigned short u16;

static __device__ __forceinline__ u16 f2bf(float f){
  unsigned u = __float_as_uint(f);
  u += 0x7FFFu + ((u >> 16) & 1u);   // RNE
  return (u16)(u >> 16);
}
static __device__ __forceinline__ float bf2f(unsigned u){
  return __uint_as_float(u << 16);
}

// async global->LDS, 16B per lane. LDS dest must be wave-uniform base (+lane*16 implicit).
static __device__ __forceinline__ void gload16(const void* g, void* l){
  __builtin_amdgcn_global_load_lds(
    (const __attribute__((address_space(1))) unsigned int*)g,
    (__attribute__((address_space(3))) unsigned int*)l, 16, 0, 0);
}

template<int N> static __device__ __forceinline__ void vmcnt(){
  asm volatile("s_waitcnt vmcnt(%0)" :: "i"(N) : "memory");
}

// ---------------- weight convert + transpose: f32 [K][N] -> bf16 [N][K] ----------------
__global__ __launch_bounds__(256) void transpose_k(const float* __restrict__ in,
    u16* __restrict__ out, int K, int N)
{
  __shared__ u16 ld[64][65];
  const int t = threadIdx.x;
  const int n0 = blockIdx.x * 64, k0 = blockIdx.y * 64;
  in  += (size_t)blockIdx.z * K * N;
  out += (size_t)blockIdx.z * K * N;
  #pragma unroll
  for (int i = 0; i < 16; ++i){
    int idx = i*256 + t; int r = idx >> 6, c = idx & 63;
    ld[r][c] = f2bf(in[(size_t)(k0 + r) * N + n0 + c]);
  }
  __syncthreads();
  #pragma unroll
  for (int i = 0; i < 16; ++i){
    int idx = i*256 + t; int c = idx >> 6, r = idx & 63;
    out[(size_t)(n0 + c) * K + k0 + r] = ld[r][c];
  }
}

// ---------------- V transpose: [B,S,NH,HD] -> [B,NH,HD,S] (bf16) ----------------
__global__ __launch_bounds__(256) void vtrans_k(const u16* __restrict__ v,
    u16* __restrict__ vt)
{
  __shared__ u16 tile[64][72];
  const int t = threadIdx.x;
  const int s0 = blockIdx.x * 64;
  const int bh = blockIdx.y;           // b*NH + h
  const int b = bh >> 4, hh = bh & 15;
  {
    int r = t >> 2, c0 = (t & 3) * 16;
    const u16* src = v + ((size_t)(b*S_LEN + s0 + r)*NH + hh)*HD + c0;
    *(short8*)&tile[r][c0]     = ((const short8*)src)[0];
    *(short8*)&tile[r][c0 + 8] = ((const short8*)src)[1];
  }
  __syncthreads();
  {
    int s = t & 63, d0 = (t >> 6) * 16;
    u16* dst = vt + ((size_t)bh * HD)*S_LEN;
    #pragma unroll
    for (int i = 0; i < 16; ++i)
      dst[(size_t)(d0 + i)*S_LEN + s0 + s] = tile[s][d0 + i];
  }
}

// ---------------- embedding gather ----------------
__global__ __launch_bounds__(256) void embed_k(const int* __restrict__ tok,
    const float* __restrict__ emb, float* __restrict__ h)
{
  int row = blockIdx.x;
  int t = tok[row];
  const f32x4* src = (const f32x4*)(emb + (size_t)t * DIM);
  f32x4* dst = (f32x4*)(h + (size_t)row * DIM);
  dst[threadIdx.x] = src[threadIdx.x];
}

// ---------------- RoPE cos/sin table ----------------
__global__ __launch_bounds__(256) void freqs_k(float* __restrict__ tab,
    const int* __restrict__ spp)
{
  int i = blockIdx.x * 256 + threadIdx.x;   // [0, S_LEN*32)
  int s = i >> 5, kk = i & 31;
  float inv = powf(10000.0f, -(float)kk * (1.0f/32.0f));
  float ang = (float)(*spp + s) * inv;
  tab[i*2]   = cosf(ang);
  tab[i*2+1] = sinf(ang);
}

// ---------------- RMSNorm -> bf16 ----------------
__global__ __launch_bounds__(256) void rmsnorm_k(const float* __restrict__ x,
    const float* __restrict__ w, u16* __restrict__ out)
{
  int row = blockIdx.x, t = threadIdx.x;
  const float* xr = x + (size_t)row * DIM;
  float v[4]; float ss = 0.f;
  #pragma unroll
  for (int i=0;i<4;i++){ v[i] = xr[t + 256*i]; ss += v[i]*v[i]; }
  #pragma unroll
  for (int o=1;o<64;o<<=1) ss += __shfl_xor(ss, o);
  __shared__ float red[4];
  if ((t & 63) == 0) red[t>>6] = ss;
  __syncthreads();
  float tot = red[0]+red[1]+red[2]+red[3];
  float rs = rsqrtf(tot * (1.0f/DIM) + 1e-6f);
  u16* orow = out + (size_t)row * DIM;
  #pragma unroll
  for (int i=0;i<4;i++) orow[t + 256*i] = f2bf(v[i]*rs*w[t+256*i]);
}

// RMSNorm of last-position rows -> f32
__global__ __launch_bounds__(256) void rmsnorm_last_k(const float* __restrict__ x,
    const float* __restrict__ w, float* __restrict__ out)
{
  int row = (blockIdx.x + 1) * S_LEN - 1;
  int t = threadIdx.x;
  const float* xr = x + (size_t)row * DIM;
  float v[4]; float ss = 0.f;
  #pragma unroll
  for (int i=0;i<4;i++){ v[i] = xr[t + 256*i]; ss += v[i]*v[i]; }
  #pragma unroll
  for (int o=1;o<64;o<<=1) ss += __shfl_xor(ss, o);
  __shared__ float red[4];
  if ((t & 63) == 0) red[t>>6] = ss;
  __syncthreads();
  float tot = red[0]+red[1]+red[2]+red[3];
  float rs = rsqrtf(tot * (1.0f/DIM) + 1e-6f);
  float* orow = out + (size_t)blockIdx.x * DIM;
  #pragma unroll
  for (int i=0;i<4;i++) orow[t + 256*i] = v[i]*rs*w[t+256*i];
}

// ---------------- RoPE apply in place on bf16 q/k ----------------
__global__ __launch_bounds__(256) void rope_k(u16* __restrict__ q,
    u16* __restrict__ k, const float* __restrict__ tab)
{
  int i = blockIdx.x * 256 + threadIdx.x;   // pair id, [0, R*DIM/2)
  int kk = i & 31;
  int hs = i >> 5;                          // (b*S+s)*NH + h
  int s = (hs >> 4) & (S_LEN - 1);
  size_t base = (size_t)hs * HD + kk * 2;
  float c  = tab[(s*32 + kk)*2];
  float sn = tab[(s*32 + kk)*2 + 1];
  unsigned qv = *(const unsigned*)(q + base);
  float a0 = bf2f(qv & 0xffffu), a1 = bf2f(qv >> 16);
  *(unsigned*)(q + base) = (unsigned)f2bf(a0*c - a1*sn) | ((unsigned)f2bf(a0*sn + a1*c) << 16);
  unsigned kv = *(const unsigned*)(k + base);
  float b0 = bf2f(kv & 0xffffu), b1 = bf2f(kv >> 16);
  *(unsigned*)(k + base) = (unsigned)f2bf(b0*c - b1*sn) | ((unsigned)f2bf(b0*sn + b1*c) << 16);
}

// ---------------- pipelined GEMM, prefetch-depth-2, counted vmcnt ----------------
// C[M,N] = A_bf16[M,K] @ Bt_bf16[N,K]^T
// BM = MT*32, BN = NT*32, BK = 32, 4 waves (2x2), 3 LDS buffers.
// Main loop never drains vmcnt to 0: steady-state keeps 2 stages (2L loads) in flight.
// Safety: buffer overwritten at iter t was last read at iter t-1; trailing barrier separates.
// EPI: 1 = outF +=, 3 = outB = bf16(acc), 4 (NB=2) = outB = bf16(silu(acc0)*acc1)
template<int EPI, int MT, int NT, int NB>
__device__ __forceinline__ void gemm_pipe(
    const u16* __restrict__ A, const u16* __restrict__ B1, const u16* __restrict__ B2,
    float* __restrict__ outF, u16* __restrict__ outB,
    int N, int K, int m0, int n0)
{
  constexpr int BM = MT*32, BN = NT*32;
  constexpr int L = (MT/2) + (NT/2)*NB;   // gload16s per wave per STAGE
  __shared__ __align__(16) u16 As[3][BM*32];
  __shared__ __align__(16) u16 Bs[3][NB*BN*32];
  const int t = threadIdx.x;
  const int lane = t & 63, wid = t >> 6;
  const int wm = wid >> 1, wn = wid & 1;
  const int l16 = lane & 15, lq = lane >> 4;
  const int srow = lane >> 2, scol = (lane & 3) * 8;
  const size_t rowK16 = (size_t)16 * K;

  const u16* ag  = A  + (size_t)(m0 + wid*(MT*8) + srow) * K + scol;
  const u16* bg1 = B1 + (size_t)(n0 + wid*(NT*8) + srow) * K + scol;
  const u16* bg2 = (NB == 2) ? (B2 + (size_t)(n0 + wid*(NT*8) + srow) * K + scol) : nullptr;

  f32x4 acc[NB][MT][NT];
  #pragma unroll
  for (int j=0;j<NB;j++)
    #pragma unroll
    for (int m=0;m<MT;m++)
      #pragma unroll
      for (int n=0;n<NT;n++) acc[j][m][n] = (f32x4){0.f,0.f,0.f,0.f};

  auto STAGE = [&](int buf, int k0){
    u16* al = &As[buf][wid*(MT*8)*32];
    #pragma unroll
    for (int pp = 0; pp < MT/2; ++pp)
      gload16(ag + pp*rowK16 + k0, al + pp*512);
    u16* bl = &Bs[buf][wid*(NT*8)*32];
    #pragma unroll
    for (int pp = 0; pp < NT/2; ++pp)
      gload16(bg1 + pp*rowK16 + k0, bl + pp*512);
    if (NB == 2) {
      u16* b2l = &Bs[buf][BN*32 + wid*(NT*8)*32];
      #pragma unroll
      for (int pp = 0; pp < NT/2; ++pp)
        gload16(bg2 + pp*rowK16 + k0, b2l + pp*512);
    }
  };

  const int nt = K >> 5;
  STAGE(0, 0);
  if (nt > 1) STAGE(1, 32);
  int rb = 0;
  for (int tt = 0; tt < nt; ++tt) {
    int pb = rb + 2; if (pb >= 3) pb -= 3;
    if (tt + 2 < nt) { STAGE(pb, (tt+2)*32); vmcnt<2*L>(); }
    else if (tt + 1 < nt) vmcnt<L>();
    else vmcnt<0>();
    __builtin_amdgcn_s_barrier();

    short8 af[MT];
    #pragma unroll
    for (int m=0;m<MT;m++) af[m] = *(const short8*)&As[rb][(wm*(MT*16) + m*16 + l16)*32 + lq*8];
    #pragma unroll
    for (int j=0;j<NB;j++){
      short8 bfr[NT];
      #pragma unroll
      for (int n=0;n<NT;n++) bfr[n] = *(const short8*)&Bs[rb][j*(BN*32) + (wn*(NT*16) + n*16 + l16)*32 + lq*8];
      #pragma unroll
      for (int m=0;m<MT;m++)
        #pragma unroll
        for (int n=0;n<NT;n++)
          acc[j][m][n] = __builtin_amdgcn_mfma_f32_16x16x32_bf16(af[m], bfr[n], acc[j][m][n], 0, 0, 0);
    }
    __builtin_amdgcn_s_barrier();
    rb = (rb + 1 == 3) ? 0 : rb + 1;
  }

  #pragma unroll
  for (int m=0;m<MT;m++){
    int row = m0 + wm*(MT*16) + m*16 + lq*4;
    #pragma unroll
    for (int n=0;n<NT;n++){
      int col = n0 + wn*(NT*16) + n*16 + l16;
      #pragma unroll
      for (int i=0;i<4;i++){
        size_t idx = (size_t)(row+i)*N + col;
        if (EPI == 1) outF[idx] += acc[0][m][n][i];
        else if (EPI == 3) outB[idx] = f2bf(acc[0][m][n][i]);
        else if (EPI == 4) {
          float v1 = acc[0][m][n][i];
          float s = v1 / (1.0f + __expf(-v1));
          outB[idx] = f2bf(s * acc[1][m][n][i]);
        }
      }
    }
  }
}

template<int EPI, int MT, int NT>
__global__ __launch_bounds__(256) void gemm_k(const u16* __restrict__ A,
    const u16* __restrict__ Bt, float* __restrict__ outF,
    u16* __restrict__ outB, int N, int K)
{
  gemm_pipe<EPI,MT,NT,1>(A, Bt, nullptr, outF, outB, N, K, blockIdx.y*(MT*32), blockIdx.x*(NT*32));
}

// fused FFN: g = bf16( silu(xn@w1) * (xn@w3) )   BM=64, BN=128 x2
__global__ __launch_bounds__(256) void gemm_ffn13_k(const u16* __restrict__ A,
    const u16* __restrict__ W1t, const u16* __restrict__ W3t, u16* __restrict__ g)
{
  gemm_pipe<4,2,4,2>(A, W1t, W3t, nullptr, g, HID, DIM, blockIdx.y*64, blockIdx.x*128);
}

// qkv: BM=128, BN=64; grid.x = 48 (3 matrices x 16 col-tiles)
__global__ __launch_bounds__(256) void gemm_qkv_k(const u16* __restrict__ A,
    const u16* __restrict__ WqT, const u16* __restrict__ WkT, const u16* __restrict__ WvT,
    u16* __restrict__ q, u16* __restrict__ k, u16* __restrict__ v)
{
  int which = blockIdx.x >> 4;
  int n0 = (blockIdx.x & 15) * 64;
  const u16* Bt = (which==0) ? WqT : (which==1 ? WkT : WvT);
  u16* o = (which==0) ? q : (which==1 ? k : v);
  gemm_pipe<3,4,2,1>(A, Bt, nullptr, nullptr, o, DIM, DIM, blockIdx.y*128, n0);
}

// ---------------- flash attention ----------------
// Q,K,O: [B,S,NH,HD] bf16; Vt: [B,NH,HD,S] bf16. 4 waves/block, 16 q-rows/wave.
__global__ __launch_bounds__(256) void attn_k(const u16* __restrict__ Q,
    const u16* __restrict__ Kt, const u16* __restrict__ Vt,
    u16* __restrict__ O, const int* __restrict__ spp)
{
  __shared__ u16 P[4][16][32];
  const float NEG_INF = -__builtin_inff();
  int t = threadIdx.x, lane = t & 63, wid = t >> 6;
  int l16 = lane & 15, lq = lane >> 4;
  int q0 = blockIdx.x * 64 + wid * 16;
  int b = blockIdx.y >> 4, hh = blockIdx.y & 15;
  int spos = *spp;
  const float scale = 0.125f;
  size_t bh = ((size_t)(b * S_LEN) * NH + hh) * HD;
  const u16* vtb = Vt + (size_t)blockIdx.y * HD * S_LEN;  // [d][s]
  #define AOFF(s, d) (bh + (size_t)(s) * (NH*HD) + (d))

  short8 qf0 = *(const short8*)(Q + AOFF(q0 + l16, lq*8));
  short8 qf1 = *(const short8*)(Q + AOFF(q0 + l16, 32 + lq*8));
  f32x4 oa[4];
  #pragma unroll
  for (int j=0;j<4;j++) oa[j] = (f32x4){0.f,0.f,0.f,0.f};
  float mrow[4] = {NEG_INF, NEG_INF, NEG_INF, NEG_INF};
  float lrow[4] = {0.f, 0.f, 0.f, 0.f};
  int nk = q0 + 16 + spos; if (nk > S_LEN) nk = S_LEN;

  for (int kb0 = 0; kb0 < nk; kb0 += 32) {
    f32x4 sv0 = (f32x4){0.f,0.f,0.f,0.f};
    {
      short8 kf0 = *(const short8*)(Kt + AOFF(kb0 + l16, lq*8));
      short8 kf1 = *(const short8*)(Kt + AOFF(kb0 + l16, 32 + lq*8));
      sv0 = __builtin_amdgcn_mfma_f32_16x16x32_bf16(qf0, kf0, sv0, 0,0,0);
      sv0 = __builtin_amdgcn_mfma_f32_16x16x32_bf16(qf1, kf1, sv0, 0,0,0);
    }
    bool have1 = (kb0 + 16 < nk);
    f32x4 sv1 = (f32x4){0.f,0.f,0.f,0.f};
    if (have1) {
      short8 kf0 = *(const short8*)(Kt + AOFF(kb0 + 16 + l16, lq*8));
      short8 kf1 = *(const short8*)(Kt + AOFF(kb0 + 16 + l16, 32 + lq*8));
      sv1 = __builtin_amdgcn_mfma_f32_16x16x32_bf16(qf0, kf0, sv1, 0,0,0);
      sv1 = __builtin_amdgcn_mfma_f32_16x16x32_bf16(qf1, kf1, sv1, 0,0,0);
    }
    #pragma unroll
    for (int r=0;r<4;r++){
      int qrow = q0 + lq*4 + r;
      float s0 = ((kb0 + l16) <= qrow + spos) ? sv0[r]*scale : NEG_INF;
      float s1 = (have1 && (kb0 + 16 + l16) <= qrow + spos) ? sv1[r]*scale : NEG_INF;
      float mt = fmaxf(s0, s1);
      mt = fmaxf(mt, __shfl_xor(mt, 1));
      mt = fmaxf(mt, __shfl_xor(mt, 2));
      mt = fmaxf(mt, __shfl_xor(mt, 4));
      mt = fmaxf(mt, __shfl_xor(mt, 8));
      float mn = fmaxf(mrow[r], mt);
      float corr = __expf(mrow[r] - mn);
      float p0 = __expf(s0 - mn);
      float p1 = __expf(s1 - mn);
      float rsum = p0 + p1;
      rsum += __shfl_xor(rsum, 1);
      rsum += __shfl_xor(rsum, 2);
      rsum += __shfl_xor(rsum, 4);
      rsum += __shfl_xor(rsum, 8);
      lrow[r] = lrow[r]*corr + rsum;
      mrow[r] = mn;
      #pragma unroll
      for (int j=0;j<4;j++) oa[j][r] *= corr;
      P[wid][lq*4 + r][l16]      = f2bf(p0);
      P[wid][lq*4 + r][16 + l16] = f2bf(p1);
    }
    short8 pf = *(const short8*)&P[wid][l16][lq*8];
    #pragma unroll
    for (int j=0;j<4;j++){
      short8 vfr = *(const short8*)(vtb + (size_t)(j*16 + l16)*S_LEN + kb0 + lq*8);
      oa[j] = __builtin_amdgcn_mfma_f32_16x16x32_bf16(pf, vfr, oa[j], 0,0,0);
    }
  }
  #pragma unroll
  for (int r=0;r<4;r++){
    float inv = 1.0f / lrow[r];
    #pragma unroll
    for (int j=0;j<4;j++)
      O[AOFF(q0 + lq*4 + r, j*16 + l16)] = f2bf(oa[j][r] * inv);
  }
  #undef AOFF
}

// ---------------- final projection: [2,1024] @ [1024,32000] ----------------
__global__ __launch_bounds__(256) void outproj_k(const float* __restrict__ xf,
    const float* __restrict__ W, float* __restrict__ out)
{
  __shared__ float xs0[512], xs1[512];
  int t = threadIdx.x;
  int kbase = blockIdx.y * 512;
  for (int i = t; i < 512; i += 256){ xs0[i] = xf[kbase + i]; xs1[i] = xf[DIM + kbase + i]; }
  __syncthreads();
  int n = blockIdx.x * 256 + t;
  float a0 = 0.f, a1 = 0.f;
  #pragma unroll 8
  for (int k2 = 0; k2 < 512; ++k2){
    float w = W[(size_t)(kbase + k2) * NVOCAB + n];
    a0 += xs0[k2]*w; a1 += xs1[k2]*w;
  }
  atomicAdd(&out[n], a0);
  atomicAdd(&out[NVOCAB + n], a1);
}

extern "C" void kernel_launch(void* const* d_in, const int* in_sizes, int n_in,
                              void* d_out, int out_size, void* d_ws, size_t ws_size,
                              hipStream_t stream)
{
  const int*   tokens = (const int*)d_in[0];
  const int*   spp    = (const int*)d_in[1];
  const float* temb   = (const float*)d_in[2];
  const float* wq     = (const float*)d_in[3];
  const float* wk     = (const float*)d_in[4];
  const float* wv     = (const float*)d_in[5];
  const float* wo     = (const float*)d_in[6];
  const float* w1     = (const float*)d_in[7];
  const float* w2     = (const float*)d_in[8];
  const float* w3     = (const float*)d_in[9];
  const float* anw    = (const float*)d_in[10];
  const float* fnw    = (const float*)d_in[11];
  const float* finw   = (const float*)d_in[12];
  const float* outw   = (const float*)d_in[13];

  char* p = (char*)d_ws;
  auto carve = [&](size_t nbytes){ char* r = p; p += (nbytes + 255) & ~(size_t)255; return r; };
  const int R = B_SZ * S_LEN;  // 2048 rows
  float* h    = (float*)carve((size_t)R*DIM*4);
  u16* xn     = (u16*)carve((size_t)R*DIM*2);
  u16* qb     = (u16*)carve((size_t)R*DIM*2);
  u16* kb     = (u16*)carve((size_t)R*DIM*2);
  u16* vb     = (u16*)carve((size_t)R*DIM*2);
  u16* vt     = (u16*)carve((size_t)R*DIM*2);
  u16* ob     = (u16*)carve((size_t)R*DIM*2);
  u16* g      = (u16*)carve((size_t)R*HID*2);
  float* tab  = (float*)carve((size_t)S_LEN*32*2*4);
  float* xfin = (float*)carve((size_t)B_SZ*DIM*4);
  // transposed bf16 weights
  u16* wqT = (u16*)carve((size_t)4*DIM*DIM*2);
  u16* wkT = (u16*)carve((size_t)4*DIM*DIM*2);
  u16* wvT = (u16*)carve((size_t)4*DIM*DIM*2);
  u16* woT = (u16*)carve((size_t)4*DIM*DIM*2);
  u16* w1T = (u16*)carve((size_t)4*DIM*HID*2);
  u16* w3T = (u16*)carve((size_t)4*DIM*HID*2);
  u16* w2T = (u16*)carve((size_t)4*HID*DIM*2);
  (void)ws_size; (void)in_sizes; (void)n_in;

  // weight convert+transpose (per call; ~310MB traffic)
  transpose_k<<<dim3(16,16,4), 256, 0, stream>>>(wq, wqT, DIM, DIM);
  transpose_k<<<dim3(16,16,4), 256, 0, stream>>>(wk, wkT, DIM, DIM);
  transpose_k<<<dim3(16,16,4), 256, 0, stream>>>(wv, wvT, DIM, DIM);
  transpose_k<<<dim3(16,16,4), 256, 0, stream>>>(wo, woT, DIM, DIM);
  transpose_k<<<dim3(44,16,4), 256, 0, stream>>>(w1, w1T, DIM, HID);
  transpose_k<<<dim3(44,16,4), 256, 0, stream>>>(w3, w3T, DIM, HID);
  transpose_k<<<dim3(16,44,4), 256, 0, stream>>>(w2, w2T, HID, DIM);

  freqs_k<<<(S_LEN*32)/256, 256, 0, stream>>>(tab, spp);
  embed_k<<<R, 256, 0, stream>>>(tokens, temb, h);

  for (int l = 0; l < 4; ++l) {
    size_t sqo = (size_t)l * DIM * DIM;
    size_t sff = (size_t)l * DIM * HID;
    rmsnorm_k<<<R, 256, 0, stream>>>(h, anw + l*DIM, xn);
    gemm_qkv_k<<<dim3(48, R/128), 256, 0, stream>>>(xn, wqT + sqo, wkT + sqo, wvT + sqo, qb, kb, vb);
    rope_k<<<(R*DIM/2)/256, 256, 0, stream>>>(qb, kb, tab);
    vtrans_k<<<dim3(S_LEN/64, B_SZ*NH), 256, 0, stream>>>(vb, vt);
    attn_k<<<dim3(S_LEN/64, B_SZ*NH), 256, 0, stream>>>(qb, kb, vt, ob, spp);
    gemm_k<1,2,2><<<dim3(DIM/64, R/64), 256, 0, stream>>>(ob, woT + sqo, h, nullptr, DIM, DIM);
    rmsnorm_k<<<R, 256, 0, stream>>>(h, fnw + l*DIM, xn);
    gemm_ffn13_k<<<dim3(HID/128, R/64), 256, 0, stream>>>(xn, w1T + sff, w3T + sff, g);
    gemm_k<1,2,2><<<dim3(DIM/64, R/64), 256, 0, stream>>>(g, w2T + sff, h, nullptr, DIM, HID);
  }
  rmsnorm_last_k<<<B_SZ, 256, 0, stream>>>(h, finw, xfin);
  hipMemsetAsync(d_out, 0, (size_t)out_size * sizeof(float), stream);
  outproj_k<<<dim3(NVOCAB/256, 2), 256, 0, stream>>>(xfin, outw, (float*)d_out);
}

// Round 6
// 912.056 us; speedup vs baseline: 1.0888x; 1.0888x over previous
//
#include <hip/hip_runtime.h>
#include <cstddef>

#define B_SZ 2
#define S_LEN 1024
#define NH 16
#define HD 64
#define DIM 1024
#define HID 2816
#define NVOCAB 32000

typedef __attribute__((ext_vector_type(8))) short short8;
typedef __attribute__((ext_vector_type(4))) float f32x4;
typedef __attribute__((ext_vector_type(4))) unsigned short u16x4;
typedef unsigned short u16;

static __device__ __forceinline__ u16 f2bf(float f){
  unsigned u = __float_as_uint(f);
  u += 0x7FFFu + ((u >> 16) & 1u);   // RNE
  return (u16)(u >> 16);
}
static __device__ __forceinline__ float bf2f(unsigned u){
  return __uint_as_float(u << 16);
}

// async global->LDS, 16B per lane. LDS dest must be wave-uniform base (+lane*16 implicit).
static __device__ __forceinline__ void gload16(const void* g, void* l){
  __builtin_amdgcn_global_load_lds(
    (const __attribute__((address_space(1))) unsigned int*)g,
    (__attribute__((address_space(3))) unsigned int*)l, 16, 0, 0);
}

// ---------------- weight convert + transpose: f32 [K][N] -> bf16 [N][K] ----------------
__global__ __launch_bounds__(256) void transpose_k(const float* __restrict__ in,
    u16* __restrict__ out, int K, int N)
{
  __shared__ u16 ld[64][65];
  const int t = threadIdx.x;
  const int n0 = blockIdx.x * 64, k0 = blockIdx.y * 64;
  in  += (size_t)blockIdx.z * K * N;
  out += (size_t)blockIdx.z * K * N;
  #pragma unroll
  for (int i = 0; i < 16; ++i){
    int idx = i*256 + t; int r = idx >> 6, c = idx & 63;
    ld[r][c] = f2bf(in[(size_t)(k0 + r) * N + n0 + c]);
  }
  __syncthreads();
  #pragma unroll
  for (int i = 0; i < 16; ++i){
    int idx = i*256 + t; int c = idx >> 6, r = idx & 63;
    out[(size_t)(n0 + c) * K + k0 + r] = ld[r][c];
  }
}

// ---------------- embedding gather ----------------
__global__ __launch_bounds__(256) void embed_k(const int* __restrict__ tok,
    const float* __restrict__ emb, float* __restrict__ h)
{
  int row = blockIdx.x;
  int t = tok[row];
  const f32x4* src = (const f32x4*)(emb + (size_t)t * DIM);
  f32x4* dst = (f32x4*)(h + (size_t)row * DIM);
  dst[threadIdx.x] = src[threadIdx.x];
}

// ---------------- RoPE cos/sin table ----------------
__global__ __launch_bounds__(256) void freqs_k(float* __restrict__ tab,
    const int* __restrict__ spp)
{
  int i = blockIdx.x * 256 + threadIdx.x;   // [0, S_LEN*32)
  int s = i >> 5, kk = i & 31;
  float inv = powf(10000.0f, -(float)kk * (1.0f/32.0f));
  float ang = (float)(*spp + s) * inv;
  tab[i*2]   = cosf(ang);
  tab[i*2+1] = sinf(ang);
}

// ---------------- RMSNorm -> bf16 ----------------
__global__ __launch_bounds__(256) void rmsnorm_k(const float* __restrict__ x,
    const float* __restrict__ w, u16* __restrict__ out)
{
  int row = blockIdx.x, t = threadIdx.x;
  const float* xr = x + (size_t)row * DIM;
  float v[4]; float ss = 0.f;
  #pragma unroll
  for (int i=0;i<4;i++){ v[i] = xr[t + 256*i]; ss += v[i]*v[i]; }
  #pragma unroll
  for (int o=1;o<64;o<<=1) ss += __shfl_xor(ss, o);
  __shared__ float red[4];
  if ((t & 63) == 0) red[t>>6] = ss;
  __syncthreads();
  float tot = red[0]+red[1]+red[2]+red[3];
  float rs = rsqrtf(tot * (1.0f/DIM) + 1e-6f);
  u16* orow = out + (size_t)row * DIM;
  #pragma unroll
  for (int i=0;i<4;i++) orow[t + 256*i] = f2bf(v[i]*rs*w[t+256*i]);
}

// RMSNorm of last-position rows -> f32
__global__ __launch_bounds__(256) void rmsnorm_last_k(const float* __restrict__ x,
    const float* __restrict__ w, float* __restrict__ out)
{
  int row = (blockIdx.x + 1) * S_LEN - 1;
  int t = threadIdx.x;
  const float* xr = x + (size_t)row * DIM;
  float v[4]; float ss = 0.f;
  #pragma unroll
  for (int i=0;i<4;i++){ v[i] = xr[t + 256*i]; ss += v[i]*v[i]; }
  #pragma unroll
  for (int o=1;o<64;o<<=1) ss += __shfl_xor(ss, o);
  __shared__ float red[4];
  if ((t & 63) == 0) red[t>>6] = ss;
  __syncthreads();
  float tot = red[0]+red[1]+red[2]+red[3];
  float rs = rsqrtf(tot * (1.0f/DIM) + 1e-6f);
  float* orow = out + (size_t)blockIdx.x * DIM;
  #pragma unroll
  for (int i=0;i<4;i++) orow[t + 256*i] = v[i]*rs*w[t+256*i];
}

// ---------------- pipelined GEMM, BK=64 (two BK=32 sub-stages), 2 buffers ----------------
// C[M,N] = A_bf16[M,K] @ Bt_bf16[N,K]^T
// BM = MT*32, BN = NT*32, 4 waves (2x2), STAGE(t+1) issued before compute(t),
// ONE __syncthreads per K-step (round-4 proven form; counted-vmcnt variant regressed).
// EPI: 1 = outF +=; 4 (NB=2) = outB = bf16(silu(acc0)*acc1);
//      5 = qkv epilogue: isv ? transposed V write [B,NH,HD,S] : RoPE -> outB
template<int EPI, int MT, int NT, int NB>
__device__ __forceinline__ void gemm_pipe(
    const u16* __restrict__ A, const u16* __restrict__ B1, const u16* __restrict__ B2,
    float* __restrict__ outF, u16* __restrict__ outB,
    const float* __restrict__ tab, int isv,
    int N, int K, int m0, int n0)
{
  constexpr int BM = MT*32, BN = NT*32;
  __shared__ __align__(16) u16 As[2][2*BM*32];       // [buf][sub*BM*32 + r*32 + c]
  __shared__ __align__(16) u16 Bs[2][2*NB*BN*32];    // [buf][(j*2+sub)*BN*32 + r*32 + c]
  const int t = threadIdx.x;
  const int lane = t & 63, wid = t >> 6;
  const int wm = wid >> 1, wn = wid & 1;
  const int l16 = lane & 15, lq = lane >> 4;
  const int srow = lane >> 2, scol = (lane & 3) * 8;
  const size_t rowK16 = (size_t)16 * K;

  const u16* ag  = A  + (size_t)(m0 + wid*(MT*8) + srow) * K + scol;
  const u16* bg1 = B1 + (size_t)(n0 + wid*(NT*8) + srow) * K + scol;
  const u16* bg2 = (NB == 2) ? (B2 + (size_t)(n0 + wid*(NT*8) + srow) * K + scol) : nullptr;

  f32x4 acc[NB][MT][NT];
  #pragma unroll
  for (int j=0;j<NB;j++)
    #pragma unroll
    for (int m=0;m<MT;m++)
      #pragma unroll
      for (int n=0;n<NT;n++) acc[j][m][n] = (f32x4){0.f,0.f,0.f,0.f};

  auto STAGE = [&](int buf, int k0){
    #pragma unroll
    for (int s = 0; s < 2; ++s){
      u16* al = &As[buf][(s*BM + wid*(MT*8))*32];
      #pragma unroll
      for (int pp = 0; pp < MT/2; ++pp)
        gload16(ag + s*32 + pp*rowK16 + k0, al + pp*512);
      u16* bl = &Bs[buf][(s*BN + wid*(NT*8))*32];
      #pragma unroll
      for (int pp = 0; pp < NT/2; ++pp)
        gload16(bg1 + s*32 + pp*rowK16 + k0, bl + pp*512);
      if (NB == 2) {
        u16* b2l = &Bs[buf][((2+s)*BN + wid*(NT*8))*32];
        #pragma unroll
        for (int pp = 0; pp < NT/2; ++pp)
          gload16(bg2 + s*32 + pp*rowK16 + k0, b2l + pp*512);
      }
    }
  };

  const int nt = K >> 6;
  STAGE(0, 0);
  __syncthreads();
  int cur = 0;
  for (int tt = 0; tt < nt; ++tt) {
    if (tt + 1 < nt) STAGE(cur ^ 1, (tt + 1) * 64);
    #pragma unroll
    for (int kk = 0; kk < 2; ++kk){
      short8 af[MT];
      #pragma unroll
      for (int m=0;m<MT;m++) af[m] = *(const short8*)&As[cur][(kk*BM + wm*(MT*16) + m*16 + l16)*32 + lq*8];
      #pragma unroll
      for (int j=0;j<NB;j++){
        short8 bfr[NT];
        #pragma unroll
        for (int n=0;n<NT;n++) bfr[n] = *(const short8*)&Bs[cur][((j*2+kk)*BN + wn*(NT*16) + n*16 + l16)*32 + lq*8];
        #pragma unroll
        for (int m=0;m<MT;m++)
          #pragma unroll
          for (int n=0;n<NT;n++)
            acc[j][m][n] = __builtin_amdgcn_mfma_f32_16x16x32_bf16(af[m], bfr[n], acc[j][m][n], 0, 0, 0);
      }
    }
    if (tt + 1 < nt) { __syncthreads(); cur ^= 1; }
  }

  #pragma unroll
  for (int m=0;m<MT;m++){
    int row = m0 + wm*(MT*16) + m*16 + lq*4;
    #pragma unroll
    for (int n=0;n<NT;n++){
      int col = n0 + wn*(NT*16) + n*16 + l16;
      if (EPI == 1){
        #pragma unroll
        for (int i=0;i<4;i++)
          outF[(size_t)(row+i)*N + col] += acc[0][m][n][i];
      } else if (EPI == 4){
        #pragma unroll
        for (int i=0;i<4;i++){
          float v1 = acc[0][m][n][i];
          float s = v1 / (1.0f + __expf(-v1));
          outB[(size_t)(row+i)*N + col] = f2bf(s * acc[1][m][n][i]);
        }
      } else if (EPI == 5){
        if (isv){
          // V: write transposed [B,NH,HD,S]; s advances with i -> packed 8B store
          int bidx = row >> 10, s0 = row & (S_LEN-1);
          int hh = col >> 6, d = col & 63;
          u16x4 pk;
          #pragma unroll
          for (int i=0;i<4;i++) pk[i] = f2bf(acc[0][m][n][i]);
          *(u16x4*)&outB[(((size_t)bidx*NH + hh)*HD + d)*S_LEN + s0] = pk;
        } else {
          // Q/K: apply RoPE; pair partner lives in lane^1 (col differs in bit 0)
          int s0 = row & (S_LEN-1);
          int d = col & 63, kk2 = d >> 1;
          float sgn = (d & 1) ? 1.f : -1.f;
          #pragma unroll
          for (int i=0;i<4;i++){
            float val = acc[0][m][n][i];
            float par = __shfl_xor(val, 1);
            float c  = tab[((s0+i)*32 + kk2)*2];
            float sn = tab[((s0+i)*32 + kk2)*2 + 1];
            outB[(size_t)(row+i)*DIM + col] = f2bf(val*c + sgn*par*sn);
          }
        }
      }
    }
  }
}

template<int EPI, int MT, int NT>
__global__ __launch_bounds__(256) void gemm_k(const u16* __restrict__ A,
    const u16* __restrict__ Bt, float* __restrict__ outF,
    u16* __restrict__ outB, int N, int K)
{
  gemm_pipe<EPI,MT,NT,1>(A, Bt, nullptr, outF, outB, nullptr, 0, N, K,
                         blockIdx.y*(MT*32), blockIdx.x*(NT*32));
}

// fused FFN: g = bf16( silu(xn@w1) * (xn@w3) )   BM=64, BN=64 x2 mats
__global__ __launch_bounds__(256) void gemm_ffn13_k(const u16* __restrict__ A,
    const u16* __restrict__ W1t, const u16* __restrict__ W3t, u16* __restrict__ g)
{
  gemm_pipe<4,2,2,2>(A, W1t, W3t, nullptr, g, nullptr, 0, HID, DIM,
                     blockIdx.y*64, blockIdx.x*64);
}

// qkv + fused rope (q,k) / transposed write (v). BM=128, BN=64; grid.x = 48.
__global__ __launch_bounds__(256) void gemm_qkv_k(const u16* __restrict__ A,
    const u16* __restrict__ WqT, const u16* __restrict__ WkT, const u16* __restrict__ WvT,
    u16* __restrict__ q, u16* __restrict__ k, u16* __restrict__ vt,
    const float* __restrict__ tab)
{
  int which = blockIdx.x >> 4;
  int n0 = (blockIdx.x & 15) * 64;
  const u16* Bt = (which==0) ? WqT : (which==1 ? WkT : WvT);
  u16* o = (which==0) ? q : (which==1 ? k : vt);
  gemm_pipe<5,4,2,1>(A, Bt, nullptr, nullptr, o, tab, which==2, DIM, DIM,
                     blockIdx.y*128, n0);
}

// ---------------- flash attention ----------------
// Q,K,O: [B,S,NH,HD] bf16; Vt: [B,NH,HD,S] bf16. 4 waves/block (no barriers), 16 q-rows/wave.
__global__ __launch_bounds__(256) void attn_k(const u16* __restrict__ Q,
    const u16* __restrict__ Kt, const u16* __restrict__ Vt,
    u16* __restrict__ O, const int* __restrict__ spp)
{
  __shared__ u16 P[4][16][32];
  const float NEG_INF = -__builtin_inff();
  int t = threadIdx.x, lane = t & 63, wid = t >> 6;
  int l16 = lane & 15, lq = lane >> 4;
  int q0 = blockIdx.x * 64 + wid * 16;
  int b = blockIdx.y >> 4, hh = blockIdx.y & 15;
  int spos = *spp;
  const float scale = 0.125f;
  size_t bh = ((size_t)(b * S_LEN) * NH + hh) * HD;
  const u16* vtb = Vt + (size_t)blockIdx.y * HD * S_LEN;  // [d][s]
  #define AOFF(s, d) (bh + (size_t)(s) * (NH*HD) + (d))

  short8 qf0 = *(const short8*)(Q + AOFF(q0 + l16, lq*8));
  short8 qf1 = *(const short8*)(Q + AOFF(q0 + l16, 32 + lq*8));
  f32x4 oa[4];
  #pragma unroll
  for (int j=0;j<4;j++) oa[j] = (f32x4){0.f,0.f,0.f,0.f};
  float mrow[4] = {NEG_INF, NEG_INF, NEG_INF, NEG_INF};
  float lrow[4] = {0.f, 0.f, 0.f, 0.f};
  int nk = q0 + 16 + spos; if (nk > S_LEN) nk = S_LEN;

  for (int kb0 = 0; kb0 < nk; kb0 += 32) {
    __builtin_amdgcn_s_setprio(1);
    f32x4 sv0 = (f32x4){0.f,0.f,0.f,0.f};
    {
      short8 kf0 = *(const short8*)(Kt + AOFF(kb0 + l16, lq*8));
      short8 kf1 = *(const short8*)(Kt + AOFF(kb0 + l16, 32 + lq*8));
      sv0 = __builtin_amdgcn_mfma_f32_16x16x32_bf16(qf0, kf0, sv0, 0,0,0);
      sv0 = __builtin_amdgcn_mfma_f32_16x16x32_bf16(qf1, kf1, sv0, 0,0,0);
    }
    bool have1 = (kb0 + 16 < nk);
    f32x4 sv1 = (f32x4){0.f,0.f,0.f,0.f};
    if (have1) {
      short8 kf0 = *(const short8*)(Kt + AOFF(kb0 + 16 + l16, lq*8));
      short8 kf1 = *(const short8*)(Kt + AOFF(kb0 + 16 + l16, 32 + lq*8));
      sv1 = __builtin_amdgcn_mfma_f32_16x16x32_bf16(qf0, kf0, sv1, 0,0,0);
      sv1 = __builtin_amdgcn_mfma_f32_16x16x32_bf16(qf1, kf1, sv1, 0,0,0);
    }
    __builtin_amdgcn_s_setprio(0);
    #pragma unroll
    for (int r=0;r<4;r++){
      int qrow = q0 + lq*4 + r;
      float s0 = ((kb0 + l16) <= qrow + spos) ? sv0[r]*scale : NEG_INF;
      float s1 = (have1 && (kb0 + 16 + l16) <= qrow + spos) ? sv1[r]*scale : NEG_INF;
      float mt = fmaxf(s0, s1);
      mt = fmaxf(mt, __shfl_xor(mt, 1));
      mt = fmaxf(mt, __shfl_xor(mt, 2));
      mt = fmaxf(mt, __shfl_xor(mt, 4));
      mt = fmaxf(mt, __shfl_xor(mt, 8));
      float mn = fmaxf(mrow[r], mt);
      float corr = __expf(mrow[r] - mn);
      float p0 = __expf(s0 - mn);
      float p1 = __expf(s1 - mn);
      float rsum = p0 + p1;
      rsum += __shfl_xor(rsum, 1);
      rsum += __shfl_xor(rsum, 2);
      rsum += __shfl_xor(rsum, 4);
      rsum += __shfl_xor(rsum, 8);
      lrow[r] = lrow[r]*corr + rsum;
      mrow[r] = mn;
      #pragma unroll
      for (int j=0;j<4;j++) oa[j][r] *= corr;
      P[wid][lq*4 + r][l16]      = f2bf(p0);
      P[wid][lq*4 + r][16 + l16] = f2bf(p1);
    }
    short8 pf = *(const short8*)&P[wid][l16][lq*8];
    __builtin_amdgcn_s_setprio(1);
    #pragma unroll
    for (int j=0;j<4;j++){
      short8 vfr = *(const short8*)(vtb + (size_t)(j*16 + l16)*S_LEN + kb0 + lq*8);
      oa[j] = __builtin_amdgcn_mfma_f32_16x16x32_bf16(pf, vfr, oa[j], 0,0,0);
    }
    __builtin_amdgcn_s_setprio(0);
  }
  #pragma unroll
  for (int r=0;r<4;r++){
    float inv = 1.0f / lrow[r];
    #pragma unroll
    for (int j=0;j<4;j++)
      O[AOFF(q0 + lq*4 + r, j*16 + l16)] = f2bf(oa[j][r] * inv);
  }
  #undef AOFF
}

// ---------------- final projection: [2,1024] @ [1024,32000] ----------------
__global__ __launch_bounds__(256) void outproj_k(const float* __restrict__ xf,
    const float* __restrict__ W, float* __restrict__ out)
{
  __shared__ float xs0[512], xs1[512];
  int t = threadIdx.x;
  int kbase = blockIdx.y * 512;
  for (int i = t; i < 512; i += 256){ xs0[i] = xf[kbase + i]; xs1[i] = xf[DIM + kbase + i]; }
  __syncthreads();
  int n = blockIdx.x * 256 + t;
  float a0 = 0.f, a1 = 0.f;
  #pragma unroll 8
  for (int k2 = 0; k2 < 512; ++k2){
    float w = W[(size_t)(kbase + k2) * NVOCAB + n];
    a0 += xs0[k2]*w; a1 += xs1[k2]*w;
  }
  atomicAdd(&out[n], a0);
  atomicAdd(&out[NVOCAB + n], a1);
}

extern "C" void kernel_launch(void* const* d_in, const int* in_sizes, int n_in,
                              void* d_out, int out_size, void* d_ws, size_t ws_size,
                              hipStream_t stream)
{
  const int*   tokens = (const int*)d_in[0];
  const int*   spp    = (const int*)d_in[1];
  const float* temb   = (const float*)d_in[2];
  const float* wq     = (const float*)d_in[3];
  const float* wk     = (const float*)d_in[4];
  const float* wv     = (const float*)d_in[5];
  const float* wo     = (const float*)d_in[6];
  const float* w1     = (const float*)d_in[7];
  const float* w2     = (const float*)d_in[8];
  const float* w3     = (const float*)d_in[9];
  const float* anw    = (const float*)d_in[10];
  const float* fnw    = (const float*)d_in[11];
  const float* finw   = (const float*)d_in[12];
  const float* outw   = (const float*)d_in[13];

  char* p = (char*)d_ws;
  auto carve = [&](size_t nbytes){ char* r = p; p += (nbytes + 255) & ~(size_t)255; return r; };
  const int R = B_SZ * S_LEN;  // 2048 rows
  float* h    = (float*)carve((size_t)R*DIM*4);
  u16* xn     = (u16*)carve((size_t)R*DIM*2);
  u16* qb     = (u16*)carve((size_t)R*DIM*2);
  u16* kb     = (u16*)carve((size_t)R*DIM*2);
  u16* vt     = (u16*)carve((size_t)R*DIM*2);
  u16* ob     = (u16*)carve((size_t)R*DIM*2);
  u16* g      = (u16*)carve((size_t)R*HID*2);
  float* tab  = (float*)carve((size_t)S_LEN*32*2*4);
  float* xfin = (float*)carve((size_t)B_SZ*DIM*4);
  // transposed bf16 weights
  u16* wqT = (u16*)carve((size_t)4*DIM*DIM*2);
  u16* wkT = (u16*)carve((size_t)4*DIM*DIM*2);
  u16* wvT = (u16*)carve((size_t)4*DIM*DIM*2);
  u16* woT = (u16*)carve((size_t)4*DIM*DIM*2);
  u16* w1T = (u16*)carve((size_t)4*DIM*HID*2);
  u16* w3T = (u16*)carve((size_t)4*DIM*HID*2);
  u16* w2T = (u16*)carve((size_t)4*HID*DIM*2);
  (void)ws_size; (void)in_sizes; (void)n_in;

  // weight convert+transpose (per call; ~310MB traffic)
  transpose_k<<<dim3(16,16,4), 256, 0, stream>>>(wq, wqT, DIM, DIM);
  transpose_k<<<dim3(16,16,4), 256, 0, stream>>>(wk, wkT, DIM, DIM);
  transpose_k<<<dim3(16,16,4), 256, 0, stream>>>(wv, wvT, DIM, DIM);
  transpose_k<<<dim3(16,16,4), 256, 0, stream>>>(wo, woT, DIM, DIM);
  transpose_k<<<dim3(44,16,4), 256, 0, stream>>>(w1, w1T, DIM, HID);
  transpose_k<<<dim3(44,16,4), 256, 0, stream>>>(w3, w3T, DIM, HID);
  transpose_k<<<dim3(16,44,4), 256, 0, stream>>>(w2, w2T, HID, DIM);

  freqs_k<<<(S_LEN*32)/256, 256, 0, stream>>>(tab, spp);
  embed_k<<<R, 256, 0, stream>>>(tokens, temb, h);

  for (int l = 0; l < 4; ++l) {
    size_t sqo = (size_t)l * DIM * DIM;
    size_t sff = (size_t)l * DIM * HID;
    rmsnorm_k<<<R, 256, 0, stream>>>(h, anw + l*DIM, xn);
    gemm_qkv_k<<<dim3(48, R/128), 256, 0, stream>>>(xn, wqT + sqo, wkT + sqo, wvT + sqo,
                                                    qb, kb, vt, tab);
    attn_k<<<dim3(S_LEN/64, B_SZ*NH), 256, 0, stream>>>(qb, kb, vt, ob, spp);
    gemm_k<1,2,2><<<dim3(DIM/64, R/64), 256, 0, stream>>>(ob, woT + sqo, h, nullptr, DIM, DIM);
    rmsnorm_k<<<R, 256, 0, stream>>>(h, fnw + l*DIM, xn);
    gemm_ffn13_k<<<dim3(HID/64, R/64), 256, 0, stream>>>(xn, w1T + sff, w3T + sff, g);
    gemm_k<1,2,2><<<dim3(DIM/64, R/64), 256, 0, stream>>>(g, w2T + sff, h, nullptr, DIM, HID);
  }
  rmsnorm_last_k<<<B_SZ, 256, 0, stream>>>(h, finw, xfin);
  hipMemsetAsync(d_out, 0, (size_t)out_size * sizeof(float), stream);
  outproj_k<<<dim3(NVOCAB/256, 2), 256, 0, stream>>>(xfin, outw, (float*)d_out);
}